// Round 2
// baseline (16242.674 us; speedup 1.0000x reference)
//
#include <hip/hip_runtime.h>
#include <cstdint>
#include <cstddef>

typedef unsigned short u16;
typedef short bf16x8 __attribute__((ext_vector_type(8)));
typedef float f32x4 __attribute__((ext_vector_type(4)));
typedef unsigned short u16x4 __attribute__((ext_vector_type(4)));

#define T_LEN 1200

// workspace byte offsets (all 256-aligned). Total ~47.9 MB.
#define O_X     0ull           // x bf16: 38400*512*2        = 39,321,600
#define O_WIH   39321600ull    // W_ih cat bf16: 4096*512*2  =  4,194,304
#define O_WHH   43515904ull    // W_hh cat bf16: 4096*512*2  =  4,194,304
#define O_BIAS  47710208ull    // bias cat f32: 4096*4       =     16,384
#define O_HBUF  47726592ull    // h dbl-buf bf16: 2*2*32*512*2 =   131,072
#define O_BAR   47857664ull    // barrier: 2 u32 (+pad)
#define WS_NEED 47857792ull

#define HO 19660800ull   // h_n offset in d_out (floats)
#define CO 19693568ull   // c_n offset in d_out (floats)

__device__ __forceinline__ u16 f2bf(float f) {
  union { float f; unsigned u; } v; v.f = f;
  unsigned r = v.u + 0x7FFFu + ((v.u >> 16) & 1u);
  return (u16)(r >> 16);
}
__device__ __forceinline__ float bf2f(u16 b) {
  union { unsigned u; float f; } v; v.u = ((unsigned)b) << 16; return v.f;
}
__device__ __forceinline__ float sigm(float x) { return 1.f / (1.f + __expf(-x)); }
__device__ __forceinline__ float tanh_s(float x) {
  float ax = fabsf(x);
  float e = __expf(-2.f * ax);          // in (0,1], no overflow
  float t = (1.f - e) / (1.f + e);
  return x < 0.f ? -t : t;
}

// ---------------- cast x (f32 -> bf16), 4 elems/thread ----------------
__global__ __launch_bounds__(256) void cast_x_k(const float4* __restrict__ x,
                                                u16* __restrict__ xb) {
  int i = blockIdx.x * 256 + threadIdx.x;   // 4,915,200 threads
  float4 v = x[i];
  u16x4 o;
  o.x = f2bf(v.x); o.y = f2bf(v.y); o.z = f2bf(v.z); o.w = f2bf(v.w);
  *(u16x4*)(xb + (size_t)i * 4) = o;
}

// ---------------- concat + cast weights, fold biases ----------------
__global__ __launch_bounds__(256) void prep_w_k(
    const float* __restrict__ wih_f, const float* __restrict__ whh_f,
    const float* __restrict__ bih_f, const float* __restrict__ bhh_f,
    const float* __restrict__ wih_b, const float* __restrict__ whh_b,
    const float* __restrict__ bih_b, const float* __restrict__ bhh_b,
    u16* __restrict__ Wih, u16* __restrict__ Whh, float* __restrict__ bias) {
  int tid = blockIdx.x * 256 + threadIdx.x;   // 0 .. 4096*512-1
  int g = tid >> 9;
  float vi, vh;
  if (g < 2048) { vi = wih_f[tid]; vh = whh_f[tid]; }
  else { int t2 = tid - (2048 * 512); vi = wih_b[t2]; vh = whh_b[t2]; }
  Wih[tid] = f2bf(vi);
  Whh[tid] = f2bf(vh);
  if ((tid & 511) == 0) {
    bias[g] = (g < 2048) ? (bih_f[g] + bhh_f[g]) : (bih_b[g - 2048] + bhh_b[g - 2048]);
  }
}

// ---------------- device-scope grid barrier (sense-reversing) ----------------
__device__ __forceinline__ void grid_bar(unsigned* bar, unsigned nb) {
  __syncthreads();
  if (threadIdx.x == 0) {
    unsigned g = __hip_atomic_load(&bar[1], __ATOMIC_RELAXED, __HIP_MEMORY_SCOPE_AGENT);
    unsigned prev = __hip_atomic_fetch_add(&bar[0], 1u, __ATOMIC_ACQ_REL, __HIP_MEMORY_SCOPE_AGENT);
    if (prev == nb - 1u) {
      __hip_atomic_store(&bar[0], 0u, __ATOMIC_RELAXED, __HIP_MEMORY_SCOPE_AGENT);
      __hip_atomic_store(&bar[1], g + 1u, __ATOMIC_RELEASE, __HIP_MEMORY_SCOPE_AGENT);
    } else {
      // acquire spin: each poll invalidates L1/L2 so we observe remote XCD writes
      while (__hip_atomic_load(&bar[1], __ATOMIC_ACQUIRE, __HIP_MEMORY_SCOPE_AGENT) == g)
        __builtin_amdgcn_s_sleep(1);
    }
  }
  __syncthreads();
}

// ---------------- elementwise LSTM cell for one (b, col) ----------------
__device__ __forceinline__ void cell(int b, int colv, int hcol, bool m, int orow,
                                     float bi, float bfv, float bg, float bo,
                                     float (*h_m)[16], float (*c_m)[16],
                                     float (*pre)[32][16],
                                     u16* __restrict__ hbw, float* __restrict__ out) {
  float hold = h_m[b][colv];
  if (m) {
    float gi = pre[0][b][colv] + bi;
    float gf = pre[1][b][colv] + bfv;
    float gg = pre[2][b][colv] + bg;
    float go = pre[3][b][colv] + bo;
    float iv = sigm(gi), fv = sigm(gf), gv = tanh_s(gg), ov = sigm(go);
    float cn = fv * c_m[b][colv] + iv * gv;
    float hn = ov * tanh_s(cn);
    c_m[b][colv] = cn;
    h_m[b][colv] = hn;
    atomicAdd(out + (size_t)(orow * 32 + b) * 512 + hcol, hn);
    hold = hn;
  }
  hbw[(size_t)b * 512 + hcol] = f2bf(hold);
}

// ---------------- persistent bidirectional LSTM recurrence ----------------
// 64 blocks: dir = bx>>5, slice = bx&31 (16 h-cols each). Both the W_hh and
// W_ih slices live in registers as MFMA B-fragments for the whole 1200-step
// loop; the input projection is fused (gates = [x_t,h] . [W_ih;W_hh]^T) so no
// P matrix is ever materialized (keeps ws under 48 MB).
__global__ __launch_bounds__(256, 1) void lstm_rec(const u16* __restrict__ X,
                                                   const u16* __restrict__ Wih,
                                                   const u16* __restrict__ Whh,
                                                   const float* __restrict__ bias,
                                                   const int* __restrict__ lengths,
                                                   u16* __restrict__ hbuf,
                                                   float* __restrict__ out,
                                                   unsigned* __restrict__ bar) {
  const int tid = threadIdx.x, lane = tid & 63, wid = tid >> 6;
  const int bx = blockIdx.x;
  const int dir = bx >> 5, slice = bx & 31, c0 = slice * 16;
  const int quad = lane >> 4, l15 = lane & 15;

  __shared__ float h_m[32][16];
  __shared__ float c_m[32][16];
  __shared__ float pre[4][32][16];
  __shared__ int len_s[32];

  if (tid < 32) len_s[tid] = lengths[tid];
  h_m[tid >> 4][tid & 15] = 0.f;          c_m[tid >> 4][tid & 15] = 0.f;
  h_m[(tid + 256) >> 4][tid & 15] = 0.f;  c_m[(tid + 256) >> 4][tid & 15] = 0.f;

  // B-fragments (resident whole loop): wave `wid` owns gate `wid` (i/f/g/o),
  // 16 gate cols. B[k][n] layout: n = l15, k = ks*32 + quad*8 + j.
  bf16x8 bh[16], bxw[16];
  {
    const size_t wrow = (size_t)(dir * 2048 + wid * 512 + c0 + l15) * 512 + quad * 8;
#pragma unroll
    for (int ks = 0; ks < 16; ++ks) {
      bh[ks]  = *(const bf16x8*)(Whh + wrow + (size_t)ks * 32);
      bxw[ks] = *(const bf16x8*)(Wih + wrow + (size_t)ks * 32);
    }
  }
  __syncthreads();

  const int b0 = tid >> 4, colv = tid & 15, b1 = b0 + 16;
  const int hcol = c0 + colv;
  const float bi  = bias[dir * 2048 + 0 * 512 + hcol];
  const float bfv = bias[dir * 2048 + 1 * 512 + hcol];
  const float bg  = bias[dir * 2048 + 2 * 512 + hcol];
  const float bo  = bias[dir * 2048 + 3 * 512 + hcol];

  for (int t = 0; t < T_LEN; ++t) {
    const u16* hb = hbuf + (size_t)((t & 1) * 32768 + dir * 16384);
    u16* hbw      = hbuf + (size_t)(((t + 1) & 1) * 32768 + dir * 16384);

    // ---- A-fragment row bases (per-lane batch, per-lane time for bwd) ----
    const int ba = l15, bb = 16 + l15;
    int lena = len_s[ba], lenb = len_s[bb];
    int tta = (dir == 0) ? t : (lena - 1 - t);  if (tta < 0) tta = 0;
    int ttb = (dir == 0) ? t : (lenb - 1 - t);  if (ttb < 0) ttb = 0;
    const u16* xrow0 = X + ((size_t)tta * 32 + ba) * 512 + quad * 8;
    const u16* xrow1 = X + ((size_t)ttb * 32 + bb) * 512 + quad * 8;
    const u16* hrow0 = hb + (size_t)ba * 512 + quad * 8;
    const u16* hrow1 = hb + (size_t)bb * 512 + quad * 8;

    // ---- fused gate GEMM: [x_t, h] . [W_ih; W_hh]^T, two independent
    //      accumulator chains (m-tiles) to pipeline MFMA latency ----
    f32x4 acc0 = {0.f, 0.f, 0.f, 0.f}, acc1 = {0.f, 0.f, 0.f, 0.f};
#pragma unroll
    for (int ks = 0; ks < 16; ++ks) {
      bf16x8 ax0 = *(const bf16x8*)(xrow0 + (size_t)ks * 32);
      bf16x8 ax1 = *(const bf16x8*)(xrow1 + (size_t)ks * 32);
      bf16x8 ah0 = *(const bf16x8*)(hrow0 + (size_t)ks * 32);
      bf16x8 ah1 = *(const bf16x8*)(hrow1 + (size_t)ks * 32);
      acc0 = __builtin_amdgcn_mfma_f32_16x16x32_bf16(ax0, bxw[ks], acc0, 0, 0, 0);
      acc1 = __builtin_amdgcn_mfma_f32_16x16x32_bf16(ax1, bxw[ks], acc1, 0, 0, 0);
      acc0 = __builtin_amdgcn_mfma_f32_16x16x32_bf16(ah0, bh[ks], acc0, 0, 0, 0);
      acc1 = __builtin_amdgcn_mfma_f32_16x16x32_bf16(ah1, bh[ks], acc1, 0, 0, 0);
    }
    // C/D layout: row (=batch in tile) = quad*4+r, col (=gate col) = l15
#pragma unroll
    for (int r = 0; r < 4; ++r) {
      pre[wid][quad * 4 + r][l15]      = acc0[r];
      pre[wid][16 + quad * 4 + r][l15] = acc1[r];
    }
    __syncthreads();

    // ---- elementwise cell update, h publish, output scatter ----
    {
      int len0 = len_s[b0], len1 = len_s[b1];
      int tt0 = (dir == 0) ? t : (len0 - 1 - t);
      int tt1 = (dir == 0) ? t : (len1 - 1 - t);
      bool m0 = (dir == 0) ? (t < len0) : (tt0 >= 0);
      bool m1 = (dir == 0) ? (t < len1) : (tt1 >= 0);
      if (tt0 < 0) tt0 = 0;
      if (tt1 < 0) tt1 = 0;
      cell(b0, colv, hcol, m0, tt0, bi, bfv, bg, bo, h_m, c_m, pre, hbw, out);
      cell(b1, colv, hcol, m1, tt1, bi, bfv, bg, bo, h_m, c_m, pre, hbw, out);
    }

    grid_bar(bar, 64u);
  }

  // finals: h_n (2,B,H), c_n (2,B,H)
  out[HO + (size_t)dir * 16384 + (size_t)b0 * 512 + hcol] = h_m[b0][colv];
  out[HO + (size_t)dir * 16384 + (size_t)b1 * 512 + hcol] = h_m[b1][colv];
  out[CO + (size_t)dir * 16384 + (size_t)b0 * 512 + hcol] = c_m[b0][colv];
  out[CO + (size_t)dir * 16384 + (size_t)b1 * 512 + hcol] = c_m[b1][colv];
}

extern "C" void kernel_launch(void* const* d_in, const int* in_sizes, int n_in,
                              void* d_out, int out_size, void* d_ws, size_t ws_size,
                              hipStream_t stream) {
  const float* x     = (const float*)d_in[0];
  const int*   lens  = (const int*)d_in[1];
  const float* wih_f = (const float*)d_in[2];
  const float* whh_f = (const float*)d_in[3];
  const float* bih_f = (const float*)d_in[4];
  const float* bhh_f = (const float*)d_in[5];
  const float* wih_b = (const float*)d_in[6];
  const float* whh_b = (const float*)d_in[7];
  const float* bih_b = (const float*)d_in[8];
  const float* bhh_b = (const float*)d_in[9];
  float* out = (float*)d_out;
  char* ws = (char*)d_ws;

  u16*      xb   = (u16*)(ws + O_X);
  u16*      Wih  = (u16*)(ws + O_WIH);
  u16*      Whh  = (u16*)(ws + O_WHH);
  float*    bias = (float*)(ws + O_BIAS);
  u16*      hbuf = (u16*)(ws + O_HBUF);
  unsigned* bar  = (unsigned*)(ws + O_BAR);

  hipMemsetAsync(hbuf, 0, 131072 + 128, stream);                // h dbl-buf + barrier
  hipMemsetAsync(d_out, 0, (size_t)out_size * 4, stream);       // out accumulated via atomics

  cast_x_k<<<19200, 256, 0, stream>>>((const float4*)x, xb);
  prep_w_k<<<8192, 256, 0, stream>>>(wih_f, whh_f, bih_f, bhh_f,
                                     wih_b, whh_b, bih_b, bhh_b, Wih, Whh, bias);
  lstm_rec<<<64, 256, 0, stream>>>(xb, Wih, Whh, bias, lens, hbuf, out, bar);
}